// Round 7
// baseline (359.695 us; speedup 1.0000x reference)
//
#include <hip/hip_runtime.h>
#include <cstdint>

typedef unsigned short u16;
typedef __attribute__((ext_vector_type(8))) short short8;
typedef __attribute__((ext_vector_type(8))) __bf16 bf16x8;
typedef __attribute__((ext_vector_type(4))) float f32x4;

#define DEV __device__ __forceinline__

DEV u16 f2bf(float f){
  uint32_t u = __float_as_uint(f);
  u += 0x7fffu + ((u >> 16) & 1u);
  return (u16)(u >> 16);
}
DEV float bf2f(u16 h){ return __uint_as_float(((uint32_t)h) << 16); }

DEV f32x4 mfma16(short8 a, short8 b, f32x4 c){
  return __builtin_amdgcn_mfma_f32_16x16x32_bf16(
      __builtin_bit_cast(bf16x8, a), __builtin_bit_cast(bf16x8, b), c, 0, 0, 0);
}

#define NN 10000
#define EE 160000
#define MPN 10112   /* 79*128  */
#define MPE 160128  /* 1251*128 */

// ---------------- CSR build ----------------
__global__ void count_k(const int* __restrict__ dst, int* __restrict__ cnt){
  int i = blockIdx.x * 256 + threadIdx.x;
  if(i < EE) atomicAdd(&cnt[dst[i]], 1);
}

__global__ void scan1_k(const int* __restrict__ cnt, int* __restrict__ offs,
                        int* __restrict__ bsum){
  __shared__ int buf[256];
  int b = blockIdx.x, tid = threadIdx.x, i = b * 256 + tid;
  int v = (i < NN) ? cnt[i] : 0;
  buf[tid] = v; __syncthreads();
  for(int d = 1; d < 256; d <<= 1){
    int t = (tid >= d) ? buf[tid - d] : 0;
    __syncthreads();
    buf[tid] += t;
    __syncthreads();
  }
  if(i < NN) offs[i] = buf[tid] - v;      // block-local exclusive
  if(tid == 255) bsum[b] = buf[255];
}

__global__ void scan23_k(int* __restrict__ offs, const int* __restrict__ bsum,
                         int* __restrict__ cursor){
  __shared__ int bpre_s;
  int b = blockIdx.x, tid = threadIdx.x;
  if(tid == 0){
    int s = 0;
    for(int i = 0; i < b; ++i) s += bsum[i];
    bpre_s = s;
  }
  __syncthreads();
  int i = b * 256 + tid;
  if(i < NN){ int v = offs[i] + bpre_s; offs[i] = v; cursor[i] = v; }
  if(i == 0) offs[NN] = EE;
}

__global__ void scatter_k(const int* __restrict__ dst, int* __restrict__ cursor,
                          int* __restrict__ eids){
  int i = blockIdx.x * 256 + threadIdx.x;
  if(i < EE){ int p = atomicAdd(&cursor[dst[i]], 1); eids[p] = i; }
}

// deterministic rank: slot(e) = offs[dst] + #{e' in bucket : e' < e}
__global__ void rank_k(const int* __restrict__ dst, const int* __restrict__ src,
                       const int* __restrict__ offs, const int* __restrict__ eids,
                       int* __restrict__ eidp, int* __restrict__ srcp){
  int e = blockIdx.x * 256 + threadIdx.x;
  if(e >= MPE) return;
  if(e >= EE){ eidp[e] = e; return; }      // pad slots -> zero rows of eabf
  int n = dst[e];
  int p0 = offs[n], p1 = offs[n + 1];
  int rk = 0;
  for(int p = p0; p < p1; ++p) rk += (eids[p] < e) ? 1 : 0;
  int slot = p0 + rk;
  eidp[slot] = e;
  srcp[slot] = src[e];
}

// ---------------- weight / input prep (single fused kernel) ----------------
struct WPack {
  const float* Wq[3]; const float* Wk[3]; const float* Wv[3];
  const float* Ws[3]; const float* We[3];
  const float* bq[3]; const float* bk[3]; const float* bv[3]; const float* bs[3];
};

#define PG0 5056                 /* xbf   : MPN*128/256 */
#define PG1 (PG0 + 20016)        /* eabf  : MPE*32/256  */
#define PG2 (PG1 + 3840)         /* Wcat/Wet : 3*1280   */
#define PG3 (PG2 + 1536)         /* WqBF/WeBF: 3*512    */
#define PG4 (PG3 + 15)           /* biasc */
#define PG5 (PG4 + 256)          /* encoders */

// Wcat rows per layer: [0,256) Wq^T | [256,512) Ws^T | [512,768) qWe (GEMM EPI5)
//                      | [768,1024) Wk^T | [1024,1280) Wv^T
__global__ __launch_bounds__(256) void prep_all_k(
    const float* __restrict__ x, const float* __restrict__ eattr, WPack P,
    const float* __restrict__ Wne, const float* __restrict__ Wee,
    u16* __restrict__ xbf, u16* __restrict__ eabf,
    u16* __restrict__ Wcat, u16* __restrict__ Wet,
    u16* __restrict__ WqBF, u16* __restrict__ WeBF,
    float* __restrict__ biasc, u16* __restrict__ Wnet, u16* __restrict__ Weet)
{
  int b = blockIdx.x, tid = threadIdx.x;
  if(b < PG0){
    int i = b * 256 + tid;
    xbf[i] = (i < NN * 128) ? f2bf(x[i]) : (u16)0;
  } else if(b < PG1){
    int i = (b - PG0) * 256 + tid;
    eabf[i] = (i < EE * 32) ? f2bf(eattr[i]) : (u16)0;
  } else if(b < PG2){
    int b2 = b - PG1; int l = b2 / 1280, r = b2 % 1280; int k = tid;
    float v;
    if(r < 256)       v = P.Wq[l][k * 256 + r];
    else if(r < 512)  v = P.Ws[l][k * 256 + (r - 256)];
    else if(r < 768){ Wet[((size_t)l * 256 + (r - 512)) * 256 + k] =
                        f2bf(P.We[l][k * 256 + (r - 512)]); return; }
    else if(r < 1024) v = P.Wk[l][k * 256 + (r - 768)];
    else              v = P.Wv[l][k * 256 + (r - 1024)];
    Wcat[((size_t)l * 1280 + r) * 256 + k] = f2bf(v);
  } else if(b < PG3){
    int b3 = b - PG2; int l = b3 >> 9, rr = b3 & 511; int t = tid;
    if(rr < 256) WqBF[((size_t)l * 256 + rr) * 256 + t] = f2bf(P.Wq[l][rr * 256 + t]);
    else         WeBF[((size_t)l * 256 + (rr - 256)) * 256 + t] = f2bf(P.We[l][(rr - 256) * 256 + t]);
  } else if(b < PG4){
    int b4 = b - PG3; int l = b4 / 5, seg = b4 % 5; int t = tid;
    float v;
    if(seg == 0)      v = P.bq[l][t];
    else if(seg == 1) v = P.bs[l][t];
    else if(seg == 2){
      const float* we = P.We[l] + (size_t)t * 256; const float* bq = P.bq[l];
      float s = 0.f;
      for(int c = 0; c < 256; ++c) s += bq[c] * we[c];
      v = s;
    }
    else if(seg == 3) v = P.bk[l][t];
    else              v = P.bv[l][t];
    biasc[(size_t)l * 1280 + seg * 256 + t] = v;
  } else {
    int n = b - PG4;
    if(tid < 128) Wnet[n * 128 + tid] = f2bf(Wne[(size_t)tid * 256 + n]);
    if(tid < 32)  Weet[n * 32 + tid]  = f2bf(Wee[(size_t)tid * 256 + n]);
  }
}

// ---------------- MFMA GEMM:  C[M,N] = A[M,K](bf16) @ Bt[N,K]^T(bf16) ----------------
// AG: gather A rows through rowmap.
// EPI 0: +bias; sec0 q / sec2 qWe -> qq bf16 (ld 512); sec1 skip -> skipOut fp32
//        (ld 256); sec3 k / sec4 v -> kvout bf16 (ld 512)
// EPI 1: +bias, relu -> bf16 (Out, ld Nld)
// EPI 3: acc + accv + skip, relu -> bf16 (accv pre-divided by denom)
// EPI 4: acc + accv + skip -> fp32
// EPI 5: plain -> bf16 (weight-prep GEMM; batched over blockIdx.z)
// All outputs staged in LDS then stored as 16B/lane vectorized chunks.
template<int BK, int EPI, int AG = 0>
__global__ __launch_bounds__(256) void gemm_k(
    const u16* __restrict__ A, const u16* __restrict__ Bt,
    const float* __restrict__ bias, void* __restrict__ Out,
    const float* __restrict__ accv, const float* __restrict__ skipS,
    const int* __restrict__ rowmap, u16* __restrict__ kvout,
    float* __restrict__ skipOut,
    int Mreal, int Nld, int K, size_t sA, size_t sB, size_t sOb)
{
  constexpr int CPR = BK / 8;           // 16B chunks per LDS row
  constexpr int SW  = (BK == 64) ? 7 : 3;
  __shared__ short8 smem8[2048];        // 32KB: Al|Bl during K-loop, stage in epilogue
  u16* Al = (u16*)smem8;
  u16* Bl = Al + 128 * BK;
  A  += (size_t)blockIdx.z * sA;
  Bt += (size_t)blockIdx.z * sB;
  Out = (void*)((char*)Out + (size_t)blockIdx.z * sOb);
  int tid = threadIdx.x, lane = tid & 63;
  int rowBase = blockIdx.x * 128, colBase = blockIdx.y * 128;
  int wave = tid >> 6, wm = wave >> 1, wn = wave & 1;
  int lr = lane & 15, lk = lane >> 4;
  f32x4 acc[4][4] = {};
  int nkt = K / BK;
  for(int kt = 0; kt < nkt; ++kt){
    __syncthreads();
    for(int ci = tid; ci < 128 * CPR; ci += 256){
      int r = ci / CPR, cb = ci % CPR;
      int ar = AG ? rowmap[rowBase + r] : (rowBase + r);
      int d = (r * CPR + (cb ^ (r & SW))) * 8;     // swizzled dest (u16 units)
      *(short8*)&Al[d] = *(const short8*)&A [(size_t)ar * K + kt * BK + cb * 8];
      *(short8*)&Bl[d] = *(const short8*)&Bt[(size_t)(colBase + r) * K + kt * BK + cb * 8];
    }
    __syncthreads();
    #pragma unroll
    for(int kk = 0; kk < BK / 32; ++kk){
      short8 af[4], bfr[4];
      #pragma unroll
      for(int m = 0; m < 4; ++m){
        int r = wm * 64 + m * 16 + lr;
        int byt = r * (BK * 2) + kk * 64 + lk * 16; byt ^= (r & SW) << 4;
        af[m] = *(const short8*)((const char*)Al + byt);
      }
      #pragma unroll
      for(int n = 0; n < 4; ++n){
        int r = wn * 64 + n * 16 + lr;
        int byt = r * (BK * 2) + kk * 64 + lk * 16; byt ^= (r & SW) << 4;
        bfr[n] = *(const short8*)((const char*)Bl + byt);
      }
      #pragma unroll
      for(int m = 0; m < 4; ++m)
        #pragma unroll
        for(int n = 0; n < 4; ++n)
          acc[m][n] = mfma16(af[m], bfr[n], acc[m][n]);
    }
  }

  // ---------- epilogue: LDS-staged, vectorized 16B stores ----------
  __syncthreads();                       // all ds_reads done before LDS reuse
  if constexpr(EPI == 0){
    int sec = colBase >> 8;              // 0 q | 1 skip | 2 qWe | 3 k | 4 v
    if(sec == 1){
      float* fs = (float*)smem8;         // [64][128] fp32, two passes
      #pragma unroll
      for(int h = 0; h < 2; ++h){
        if(wm == h){
          #pragma unroll
          for(int m = 0; m < 4; ++m)
            #pragma unroll
            for(int n = 0; n < 4; ++n){
              int cc = wn * 64 + n * 16 + lr;
              #pragma unroll
              for(int j = 0; j < 4; ++j){
                int r2 = m * 16 + lk * 4 + j;
                fs[r2 * 128 + cc] = acc[m][n][j] + bias[colBase + cc];
              }
            }
        }
        __syncthreads();
        for(int ch = tid; ch < 2048; ch += 256){
          int rr = ch >> 5, cc = (ch & 31) << 2;
          int r = rowBase + h * 64 + rr;
          if(r < Mreal)
            *(float4*)&skipOut[(size_t)r * 256 + (colBase - 256) + cc] = *(float4*)&fs[rr * 128 + cc];
        }
        __syncthreads();
      }
    } else {
      u16* us = (u16*)smem8;             // [128][128] bf16
      #pragma unroll
      for(int m = 0; m < 4; ++m)
        #pragma unroll
        for(int n = 0; n < 4; ++n){
          int cc = wn * 64 + n * 16 + lr;
          #pragma unroll
          for(int j = 0; j < 4; ++j){
            int rr = wm * 64 + m * 16 + lk * 4 + j;
            us[rr * 128 + cc] = f2bf(acc[m][n][j] + bias[colBase + cc]);
          }
        }
      __syncthreads();
      u16* dstp; int cofs;
      if(sec == 0){ dstp = (u16*)Out; cofs = colBase; }
      else if(sec == 2){ dstp = (u16*)Out; cofs = colBase - 256; }
      else { dstp = kvout; cofs = colBase - 768; }
      for(int ch = tid; ch < 2048; ch += 256){
        int rr = ch >> 4, cc = (ch & 15) << 3;
        int r = rowBase + rr;
        if(r < Mreal)
          *(short8*)&dstp[(size_t)r * 512 + cofs + cc] = *(short8*)&us[rr * 128 + cc];
      }
    }
  } else if constexpr(EPI == 4){
    float* fs = (float*)smem8;           // [64][128] fp32, two passes
    #pragma unroll
    for(int h = 0; h < 2; ++h){
      if(wm == h){
        #pragma unroll
        for(int m = 0; m < 4; ++m)
          #pragma unroll
          for(int n = 0; n < 4; ++n){
            int cc = wn * 64 + n * 16 + lr;
            int c = colBase + cc;
            #pragma unroll
            for(int j = 0; j < 4; ++j){
              int r2 = m * 16 + lk * 4 + j;
              int r = rowBase + h * 64 + r2;
              fs[r2 * 128 + cc] = acc[m][n][j]
                + accv[(size_t)r * 256 + c] + skipS[(size_t)r * 256 + c];
            }
          }
      }
      __syncthreads();
      for(int ch = tid; ch < 2048; ch += 256){
        int rr = ch >> 5, cc = (ch & 31) << 2;
        int r = rowBase + h * 64 + rr;
        if(r < Mreal)
          *(float4*)&((float*)Out)[(size_t)r * Nld + colBase + cc] = *(float4*)&fs[rr * 128 + cc];
      }
      __syncthreads();
    }
  } else {
    // bf16 single-pass: EPI 1 (bias+relu), 3 (accv+skip+relu), 5 (plain)
    u16* us = (u16*)smem8;               // [128][128] bf16
    #pragma unroll
    for(int m = 0; m < 4; ++m)
      #pragma unroll
      for(int n = 0; n < 4; ++n){
        int cc = wn * 64 + n * 16 + lr;
        int c = colBase + cc;
        #pragma unroll
        for(int j = 0; j < 4; ++j){
          int rr = wm * 64 + m * 16 + lk * 4 + j;
          float v = acc[m][n][j];
          if constexpr(EPI == 1){ v += bias[c]; v = fmaxf(v, 0.f); }
          else if constexpr(EPI == 3){
            int r = rowBase + rr;
            v += accv[(size_t)r * 256 + c] + skipS[(size_t)r * 256 + c];
            v = fmaxf(v, 0.f);
          }
          us[rr * 128 + cc] = f2bf(v);
        }
      }
    __syncthreads();
    for(int ch = tid; ch < 2048; ch += 256){
      int rr = ch >> 4, cc = (ch & 15) << 3;
      int r = rowBase + rr;
      if(r < Mreal)
        *(short8*)&((u16*)Out)[(size_t)r * Nld + colBase + cc] = *(short8*)&us[rr * 128 + cc];
    }
  }
}

// ---------------- fused per-node attention pass ----------------
// qq row (ld 512 bf16): q[0:256) qWe[256:512)
// kvbf row (ld 512 bf16): k[0:256) v[256:512)
// efp row (ld 256 bf16): edge features in CSR slot order
// ONE 16-lane group per node (16 nodes/block); srcp broadcast; 2-edge unroll.
__global__ __launch_bounds__(256) void node_pass_k(
    const u16* __restrict__ qq, const u16* __restrict__ efp,
    const u16* __restrict__ kvbf,
    const int* __restrict__ srcp, const int* __restrict__ offs,
    float* __restrict__ accv, u16* __restrict__ aggef)
{
  int tid = threadIdx.x, lane = tid & 63;
  int li = lane & 15, gb = lane & 48;
  int n = blockIdx.x * 16 + (tid >> 4);
  if(n >= NN) return;
  const u16* qrow = qq + (size_t)n * 512 + li * 16;
  short8 qh0 = *(const short8*)(qrow),       qh1 = *(const short8*)(qrow + 8);
  short8 eh0 = *(const short8*)(qrow + 256), eh1 = *(const short8*)(qrow + 264);
  float q[16], e[16];
  #pragma unroll
  for(int d = 0; d < 8; ++d){
    q[d] = bf2f((u16)qh0[d]); q[8 + d] = bf2f((u16)qh1[d]);
    e[d] = bf2f((u16)eh0[d]); e[8 + d] = bf2f((u16)eh1[d]);
  }
  float av[16], ag[16];
  #pragma unroll
  for(int d = 0; d < 16; ++d){ av[d] = 0.f; ag[d] = 0.f; }
  float den = 0.f;
  int p0 = offs[n], deg = offs[n + 1] - p0;
  for(int base = 0; base < deg; base += 16){
    int scnt = deg - base; if(scnt > 16) scnt = 16;
    int ssrc = (li < scnt) ? srcp[p0 + base + li] : 0;  // one coalesced read / 16 edges
    int jj = 0;
    for(; jj + 1 < scnt; jj += 2){
      int s1 = __shfl(ssrc, gb + jj);
      int s2 = __shfl(ssrc, gb + jj + 1);
      size_t p1 = (size_t)(p0 + base + jj);
      const u16* kv1 = kvbf + ((size_t)s1 << 9) + li * 16;
      const u16* kv2 = kvbf + ((size_t)s2 << 9) + li * 16;
      const u16* e1 = efp + (p1 << 8) + li * 16;
      const u16* e2 = efp + ((p1 + 1) << 8) + li * 16;
      short8 kA1 = *(const short8*)(kv1),       kB1 = *(const short8*)(kv1 + 8);
      short8 vA1 = *(const short8*)(kv1 + 256), vB1 = *(const short8*)(kv1 + 264);
      short8 fA1 = *(const short8*)(e1),        fB1 = *(const short8*)(e1 + 8);
      short8 kA2 = *(const short8*)(kv2),       kB2 = *(const short8*)(kv2 + 8);
      short8 vA2 = *(const short8*)(kv2 + 256), vB2 = *(const short8*)(kv2 + 264);
      short8 fA2 = *(const short8*)(e2),        fB2 = *(const short8*)(e2 + 8);
      float sc1 = 0.f, sc2 = 0.f;
      #pragma unroll
      for(int d = 0; d < 8; ++d){
        sc1 += q[d]   * bf2f((u16)kA1[d]) + e[d]   * bf2f((u16)fA1[d]);
        sc1 += q[8+d] * bf2f((u16)kB1[d]) + e[8+d] * bf2f((u16)fB1[d]);
        sc2 += q[d]   * bf2f((u16)kA2[d]) + e[d]   * bf2f((u16)fA2[d]);
        sc2 += q[8+d] * bf2f((u16)kB2[d]) + e[8+d] * bf2f((u16)fB2[d]);
      }
      sc1 += __shfl_xor(sc1, 1); sc2 += __shfl_xor(sc2, 1);
      sc1 += __shfl_xor(sc1, 2); sc2 += __shfl_xor(sc2, 2);
      sc1 += __shfl_xor(sc1, 4); sc2 += __shfl_xor(sc2, 4);
      sc1 += __shfl_xor(sc1, 8); sc2 += __shfl_xor(sc2, 8);
      float w1 = __expf(sc1 * 0.0625f);
      float w2 = __expf(sc2 * 0.0625f);
      den += w1 + w2;
      #pragma unroll
      for(int d = 0; d < 8; ++d){
        av[d]   += w1 * bf2f((u16)vA1[d]) + w2 * bf2f((u16)vA2[d]);
        av[8+d] += w1 * bf2f((u16)vB1[d]) + w2 * bf2f((u16)vB2[d]);
        ag[d]   += w1 * bf2f((u16)fA1[d]) + w2 * bf2f((u16)fA2[d]);
        ag[8+d] += w1 * bf2f((u16)fB1[d]) + w2 * bf2f((u16)fB2[d]);
      }
    }
    if(jj < scnt){
      int s = __shfl(ssrc, gb + jj);
      size_t p = (size_t)(p0 + base + jj);
      const u16* kvp = kvbf + ((size_t)s << 9) + li * 16;
      const u16* ep = efp + (p << 8) + li * 16;
      short8 kA = *(const short8*)(kvp),       kB = *(const short8*)(kvp + 8);
      short8 vA = *(const short8*)(kvp + 256), vB = *(const short8*)(kvp + 264);
      short8 fA = *(const short8*)(ep),        fB = *(const short8*)(ep + 8);
      float part = 0.f;
      #pragma unroll
      for(int d = 0; d < 8; ++d){
        part += q[d]   * bf2f((u16)kA[d]) + e[d]   * bf2f((u16)fA[d]);
        part += q[8+d] * bf2f((u16)kB[d]) + e[8+d] * bf2f((u16)fB[d]);
      }
      part += __shfl_xor(part, 1);
      part += __shfl_xor(part, 2);
      part += __shfl_xor(part, 4);
      part += __shfl_xor(part, 8);
      float wgt = __expf(part * 0.0625f);
      den += wgt;
      #pragma unroll
      for(int d = 0; d < 8; ++d){
        av[d]   += wgt * bf2f((u16)vA[d]);
        av[8+d] += wgt * bf2f((u16)vB[d]);
        ag[d]   += wgt * bf2f((u16)fA[d]);
        ag[8+d] += wgt * bf2f((u16)fB[d]);
      }
    }
  }
  float rden = 1.f / fmaxf(den, 1e-16f);          // pre-divide (linear in We)
  float* ao = accv + (size_t)n * 256 + li * 16;
  #pragma unroll
  for(int t = 0; t < 4; ++t){
    float4 o;
    o.x = av[t*4+0] * rden; o.y = av[t*4+1] * rden;
    o.z = av[t*4+2] * rden; o.w = av[t*4+3] * rden;
    *(float4*)(ao + t * 4) = o;
  }
  u16* go = aggef + (size_t)n * 256 + li * 16;
  #pragma unroll
  for(int t = 0; t < 2; ++t){
    short8 o;
    #pragma unroll
    for(int d = 0; d < 8; ++d) o[d] = (short)f2bf(ag[t*8+d] * rden);
    *(short8*)(go + t * 8) = o;
  }
}

// ---------------- launch ----------------
extern "C" void kernel_launch(void* const* d_in, const int* in_sizes, int n_in,
                              void* d_out, int out_size, void* d_ws, size_t ws_size,
                              hipStream_t stream){
  const float* x     = (const float*)d_in[0];
  const float* eattr = (const float*)d_in[1];
  const int*   src   = (const int*)d_in[2];
  const int*   dst   = (const int*)d_in[3];
  const float* Wee   = (const float*)d_in[4];
  const float* bee   = (const float*)d_in[5];
  const float* Wne   = (const float*)d_in[6];
  const float* bne   = (const float*)d_in[7];
  WPack P;
  for(int l = 0; l < 3; ++l){
    const int b = 8 + l * 9;
    P.Wq[l] = (const float*)d_in[b + 0]; P.bq[l] = (const float*)d_in[b + 1];
    P.Wk[l] = (const float*)d_in[b + 2]; P.bk[l] = (const float*)d_in[b + 3];
    P.Wv[l] = (const float*)d_in[b + 4]; P.bv[l] = (const float*)d_in[b + 5];
    P.We[l] = (const float*)d_in[b + 6];
    P.Ws[l] = (const float*)d_in[b + 7]; P.bs[l] = (const float*)d_in[b + 8];
  }

  char* w = (char*)d_ws; size_t off = 0;
  auto alloc = [&](size_t bytes)->char*{
    char* p = w + off; off = (off + bytes + 255) & ~(size_t)255; return p;
  };
  u16*   Wcat  = (u16*)  alloc((size_t)3 * 1280 * 256 * 2);
  u16*   Wet   = (u16*)  alloc((size_t)3 * 256 * 256 * 2);
  u16*   WqBF  = (u16*)  alloc((size_t)3 * 256 * 256 * 2);
  u16*   WeBF  = (u16*)  alloc((size_t)3 * 256 * 256 * 2);
  float* biasc = (float*)alloc((size_t)3 * 1280 * 4);
  u16*   Wnet  = (u16*)  alloc((size_t)256 * 128 * 2);
  u16*   Weet  = (u16*)  alloc((size_t)256 * 32 * 2);
  u16*   xbf   = (u16*)  alloc((size_t)MPN * 128 * 2);
  u16*   eabf  = (u16*)  alloc((size_t)MPE * 32 * 2);
  u16*   hbf   = (u16*)  alloc((size_t)MPN * 256 * 2);
  u16*   qq    = (u16*)  alloc((size_t)MPN * 512 * 2);
  float* skipf = (float*)alloc((size_t)MPN * 256 * 4);
  u16*   kvbf  = (u16*)  alloc((size_t)MPN * 512 * 2);
  u16*   efp   = (u16*)  alloc((size_t)MPE * 256 * 2);
  int*   cnt   = (int*)  alloc((size_t)NN * 4);
  int*   offs  = (int*)  alloc((size_t)(NN + 1) * 4);
  int*   cursor= (int*)  alloc((size_t)NN * 4);
  int*   bsum  = (int*)  alloc((size_t)64 * 4);
  int*   eids  = (int*)  alloc((size_t)EE * 4);
  int*   eidp  = (int*)  alloc((size_t)MPE * 4);
  int*   srcp  = (int*)  alloc((size_t)EE * 4);
  float* accv  = (float*)alloc((size_t)MPN * 256 * 4);
  u16*   aggef = (u16*)  alloc((size_t)MPN * 256 * 2);
  if(off > ws_size) return;   // workspace too small -> visible validation failure

  // CSR build (deterministic: rank-by-edge-id, no sort)
  hipMemsetAsync(cnt, 0, (size_t)NN * 4, stream);
  count_k <<<(EE + 255) / 256, 256, 0, stream>>>(dst, cnt);
  scan1_k <<<40, 256, 0, stream>>>(cnt, offs, bsum);
  scan23_k<<<40, 256, 0, stream>>>(offs, bsum, cursor);
  scatter_k<<<(EE + 255) / 256, 256, 0, stream>>>(dst, cursor, eids);
  rank_k  <<<(MPE + 255) / 256, 256, 0, stream>>>(dst, src, offs, eids, eidp, srcp);

  // all input/weight conversion in one launch
  prep_all_k<<<PG5, 256, 0, stream>>>(x, eattr, P, Wne, Wee,
      xbf, eabf, Wcat, Wet, WqBF, WeBF, biasc, Wnet, Weet);

  // qWe weight for all 3 layers in one launch (blockIdx.z = layer)
  gemm_k<64,5><<<dim3(2, 2, 3), 256, 0, stream>>>(
      WeBF, WqBF, nullptr, Wcat + (size_t)512 * 256,
      nullptr, nullptr, nullptr, nullptr, nullptr, 256, 256, 256,
      (size_t)256 * 256, (size_t)256 * 256, (size_t)1280 * 256 * 2);

  // node encoder: h = relu(x @ Wne + bne)  -> bf16
  gemm_k<64,1><<<dim3(MPN / 128, 2), 256, 0, stream>>>(
      xbf, Wnet, bne, hbf, nullptr, nullptr, nullptr, nullptr, nullptr,
      NN, 256, 128, 0, 0, 0);
  // edge encoder: ef = relu(edge_attr @ Wee + bee) -> bf16, CSR order via A-gather
  gemm_k<32,1,1><<<dim3(MPE / 128, 2), 256, 0, stream>>>(
      eabf, Weet, bee, efp, nullptr, nullptr, eidp, nullptr, nullptr,
      EE, 256, 32, 0, 0, 0);

  for(int l = 0; l < 3; ++l){
    // fused q|skip|qWe|k|v slab -> qq bf16 + skipf fp32 + kv bf16
    gemm_k<64,0><<<dim3(MPN / 128, 10), 256, 0, stream>>>(
        hbf, Wcat + (size_t)l * 1280 * 256, biasc + (size_t)l * 1280, qq,
        nullptr, nullptr, nullptr, kvbf, skipf, NN, 512, 256, 0, 0, 0);
    // per-node attention: scores + exp + weighted sums (pre-divided by denom)
    node_pass_k<<<625, 256, 0, stream>>>(qq, efp, kvbf, srcp, offs, accv, aggef);
    // out = accv + aggef@We + skip  (+relu, bf16 for layers 0,1; fp32 out for layer 2)
    if(l < 2)
      gemm_k<64,3><<<dim3(MPN / 128, 2), 256, 0, stream>>>(
          aggef, Wet + (size_t)l * 256 * 256, nullptr, hbf,
          accv, skipf, nullptr, nullptr, nullptr, NN, 256, 256, 0, 0, 0);
    else
      gemm_k<64,4><<<dim3(MPN / 128, 2), 256, 0, stream>>>(
          aggef, Wet + (size_t)l * 256 * 256, nullptr, d_out,
          accv, skipf, nullptr, nullptr, nullptr, NN, 256, 256, 0, 0, 0);
  }
}